// Round 5
// baseline (282.661 us; speedup 1.0000x reference)
//
#include <hip/hip_runtime.h>
#include <math.h>

#define N_NODES 50000
#define DEG 16
#define E_EDGES (N_NODES * DEG)
#define FIN 128
#define FTOT 192   // 2*FQK + FV
#define FQK 64
#define FV 64
#define H 8
#define NBLK 782   // ceil(50000/64)

typedef __attribute__((ext_vector_type(8))) short short8;
typedef __attribute__((ext_vector_type(4))) float float4v;

__device__ inline unsigned short f2bf(float f) {
    unsigned int u = __float_as_uint(f);
    unsigned int r = u + 0x7fffu + ((u >> 16) & 1u);  // RNE
    return (unsigned short)(r >> 16);
}

#define LDC 194   // 192 + 2 bf16 pad for the epilogue transpose

// ---------------- fused: gemm (phase A) + manual grid barrier + attention (phase B) ----
// 782 blocks x 256 thr. __launch_bounds__(256,4) caps VGPR at 128 -> >=4 blocks/CU
// by VGPR, 6 by LDS (25088B) -> capacity 1024 >= 782: all blocks co-resident, so a
// device-scope atomic counter barrier cannot deadlock (Guideline 16 pattern).
__global__ __launch_bounds__(256, 4) void fused(const float* __restrict__ x,
                                                const float* __restrict__ W,
                                                const int* __restrict__ dest,
                                                unsigned short* __restrict__ qkv,
                                                unsigned int* __restrict__ bar,
                                                float* __restrict__ out) {
    __shared__ unsigned short Bt[12544];   // 25088 B: B half-image (24576) / Ct (24832)
    const int tid = threadIdx.x;
    const int wave = tid >> 6, lane = tid & 63;

    // ================= Phase A: qkv = x @ W (bf16 MFMA), 64 rows/block =================
    {
        const int m = lane & 15, q = lane >> 4;
        const int row = blockIdx.x * 64 + wave * 16 + m;
        const int rowc = min(row, N_NODES - 1);

        // A fragments first so x-load latency hides under W staging
        short8 a[4];
        const float* xr = x + (size_t)rowc * FIN;
#pragma unroll
        for (int s = 0; s < 4; s++) {
            float4v f0 = *(const float4v*)(xr + s * 32 + q * 8);
            float4v f1 = *(const float4v*)(xr + s * 32 + q * 8 + 4);
            short8 av;
            av[0] = (short)f2bf(f0.x); av[1] = (short)f2bf(f0.y);
            av[2] = (short)f2bf(f0.z); av[3] = (short)f2bf(f0.w);
            av[4] = (short)f2bf(f1.x); av[5] = (short)f2bf(f1.y);
            av[6] = (short)f2bf(f1.z); av[7] = (short)f2bf(f1.w);
            a[s] = av;
        }

        float4v acc[12];
#pragma unroll
        for (int ct = 0; ct < 12; ct++) acc[ct] = (float4v){0.f, 0.f, 0.f, 0.f};

        // two halves of 96 cols: stage W (fp32->bf16, XOR-swizzled) then 6 col-tiles MFMA
#pragma unroll
        for (int h = 0; h < 2; h++) {
#pragma unroll
            for (int i = 0; i < 6; i++) {
                const int c = i * 256 + tid;          // 0..1535
                const int n = c % 96, kg = c / 96;    // local col, k-group (8 k's)
                unsigned short tmp[8];
#pragma unroll
                for (int j = 0; j < 8; j++)
                    tmp[j] = f2bf(W[(kg * 8 + j) * FTOT + h * 96 + n]);  // coalesced in n
                const int cs = (n * 16 + kg) ^ (n & 7);                  // XOR swizzle
                *(uint4*)(&Bt[cs * 8]) = *(const uint4*)tmp;
            }
            __syncthreads();
#pragma unroll
            for (int j = 0; j < 6; j++) {
                const int nl = j * 16 + m;            // local col in this half
                const int sw = (nl & 7) << 4;
#pragma unroll
                for (int s = 0; s < 4; s++) {
                    const short8 b = *(const short8*)((const char*)Bt +
                                     (((nl << 8) + s * 64 + q * 16) ^ sw));
                    acc[h * 6 + j] =
                        __builtin_amdgcn_mfma_f32_16x16x32_bf16(a[s], b, acc[h * 6 + j], 0, 0, 0);
                }
            }
            __syncthreads();   // reads done; safe to overwrite Bt (next half / Ct)
        }

        // transpose into interleaved-layout LDS tile (q pre-scaled)
        // acc[ct] holds col ct*16+m  (h*96+j*16+m == (h*6+j)*16+m for this geometry)
        unsigned short* Ct = Bt;
        const int lrow0 = wave * 16 + q * 4;
#pragma unroll
        for (int ct = 0; ct < 12; ct++) {
            const int col = ct * 16 + m;
            int off; float scale;
            if (col < FQK)          { off = col;                      scale = 0.35355339059327373f; }
            else if (col < 2 * FQK) { off = 64 + 2 * (col - 64);      scale = 1.f; }  // k
            else                    { off = 64 + 2 * (col - 128) + 1; scale = 1.f; }  // v
#pragma unroll
            for (int i = 0; i < 4; i++)
                Ct[(lrow0 + i) * LDC + off] = f2bf(acc[ct][i] * scale);
        }
        __syncthreads();

        // coalesced store: 64 rows x 96 dwords
        unsigned int* qg = (unsigned int*)qkv;
        const int base = blockIdx.x * 64;
#pragma unroll
        for (int i = 0; i < 24; i++) {
            int l = tid + i * 256;
            int r = l / 96, dw = l - r * 96;
            if (base + r < N_NODES)
                qg[(size_t)(base + r) * 96 + dw] = *(const unsigned int*)(&Ct[r * LDC + 2 * dw]);
        }
    }

    // ===================== manual grid barrier (device scope) =====================
    __threadfence();   // release: drain + write back this XCD's dirty qkv lines
    if (tid == 0) {
        __hip_atomic_fetch_add(bar, 1u, __ATOMIC_RELAXED, __HIP_MEMORY_SCOPE_AGENT);
        while (__hip_atomic_load(bar, __ATOMIC_RELAXED, __HIP_MEMORY_SCOPE_AGENT) < NBLK)
            __builtin_amdgcn_s_sleep(1);
    }
    __syncthreads();
    __threadfence();   // acquire: invalidate stale L2 lines before cross-block reads

    // ================= Phase B: attention, 64 nodes/block, 16/wave =================
    // lane = 4*g + r: edge g (0..15), quarter r owns heads 2r,2r+1 (dims 16r..16r+15).
    {
        const int g = lane >> 2;
        const int r = lane & 3;
        int node = blockIdx.x * 64 + wave;   // advances by 4 per iteration

        // prefetch t=0 dest + q (clamped so loads stay in bounds)
        int nodec = min(node, N_NODES - 1);
        int d = dest[nodec * DEG + g];
        const unsigned short* qp0 = qkv + (size_t)nodec * FTOT + 16 * r;
        uint4 qv0 = *(const uint4*)(qp0);
        uint4 qv1 = *(const uint4*)(qp0 + 8);

#pragma unroll 1
        for (int t = 0; t < 16; ++t) {
            // issue kv gathers for current node first (longest latency)
            const unsigned short* kp = qkv + (size_t)d * FTOT + 64 + 32 * r;
            const uint4 kv0 = *(const uint4*)(kp);
            const uint4 kv1 = *(const uint4*)(kp + 8);
            const uint4 kv2 = *(const uint4*)(kp + 16);
            const uint4 kv3 = *(const uint4*)(kp + 24);

            // prefetch next iteration's dest + q (independent of the kv gathers)
            const int noden = node + 4;
            int dN = d; uint4 nq0 = qv0, nq1 = qv1;
            if (t < 15) {
                const int nc = min(noden, N_NODES - 1);
                dN = dest[nc * DEG + g];
                const unsigned short* nqp = qkv + (size_t)nc * FTOT + 16 * r;
                nq0 = *(const uint4*)(nqp);
                nq1 = *(const uint4*)(nqp + 8);
            }

            const unsigned int qw[8]  = {qv0.x, qv0.y, qv0.z, qv0.w, qv1.x, qv1.y, qv1.z, qv1.w};
            const unsigned int kvw[16] = {kv0.x, kv0.y, kv0.z, kv0.w, kv1.x, kv1.y, kv1.z, kv1.w,
                                          kv2.x, kv2.y, kv2.z, kv2.w, kv3.x, kv3.y, kv3.z, kv3.w};
            // kvw[u] = { k[16r+u] (lo), v[16r+u] (hi) }

            float la = 0.f, lb = 0.f;   // logits for heads 2r, 2r+1 of edge g
#pragma unroll
            for (int f = 0; f < 8; f++) {
                const unsigned int qa = qw[f >> 1];
                const unsigned int qb = qw[(f + 8) >> 1];
                const float qfa = __uint_as_float((f & 1) ? (qa & 0xffff0000u) : (qa << 16));
                const float qfb = __uint_as_float((f & 1) ? (qb & 0xffff0000u) : (qb << 16));
                la = fmaf(qfa, __uint_as_float(kvw[f] << 16), la);
                lb = fmaf(qfb, __uint_as_float(kvw[f + 8] << 16), lb);
            }

            // per-head max over the 16 edges (xor over g-bits)
            float ma = la, mb = lb;
            ma = fmaxf(ma, __shfl_xor(ma, 4, 64));  mb = fmaxf(mb, __shfl_xor(mb, 4, 64));
            ma = fmaxf(ma, __shfl_xor(ma, 8, 64));  mb = fmaxf(mb, __shfl_xor(mb, 8, 64));
            ma = fmaxf(ma, __shfl_xor(ma, 16, 64)); mb = fmaxf(mb, __shfl_xor(mb, 16, 64));
            ma = fmaxf(ma, __shfl_xor(ma, 32, 64)); mb = fmaxf(mb, __shfl_xor(mb, 32, 64));
            const float pa = __expf(la - ma);
            const float pb = __expf(lb - mb);
            float sa = pa, sb = pb;
            sa += __shfl_xor(sa, 4, 64);  sb += __shfl_xor(sb, 4, 64);
            sa += __shfl_xor(sa, 8, 64);  sb += __shfl_xor(sb, 8, 64);
            sa += __shfl_xor(sa, 16, 64); sb += __shfl_xor(sb, 16, 64);
            sa += __shfl_xor(sa, 32, 64); sb += __shfl_xor(sb, 32, 64);

            // weighted v contribution, then distributed butterfly sum (all static indices)
            float o[16];
#pragma unroll
            for (int w = 0; w < 8; w++) {
                o[w]     = pa * __uint_as_float(kvw[w] & 0xffff0000u);
                o[w + 8] = pb * __uint_as_float(kvw[w + 8] & 0xffff0000u);
            }
            {   // round 1: m2=4, h=8
                const bool up = (lane & 4) != 0;
#pragma unroll
                for (int j = 0; j < 8; j++) {
                    const float send = up ? o[j] : o[j + 8];
                    const float recv = __shfl_xor(send, 4, 64);
                    o[j] = (up ? o[j + 8] : o[j]) + recv;
                }
            }
            {   // round 2: m2=8, h=4
                const bool up = (lane & 8) != 0;
#pragma unroll
                for (int j = 0; j < 4; j++) {
                    const float send = up ? o[j] : o[j + 4];
                    const float recv = __shfl_xor(send, 8, 64);
                    o[j] = (up ? o[j + 4] : o[j]) + recv;
                }
            }
            {   // round 3: m2=16, h=2
                const bool up = (lane & 16) != 0;
#pragma unroll
                for (int j = 0; j < 2; j++) {
                    const float send = up ? o[j] : o[j + 2];
                    const float recv = __shfl_xor(send, 16, 64);
                    o[j] = (up ? o[j + 2] : o[j]) + recv;
                }
            }
            {   // round 4: m2=32, h=1
                const bool up = (lane & 32) != 0;
                const float send = up ? o[0] : o[1];
                const float recv = __shfl_xor(send, 32, 64);
                o[0] = (up ? o[1] : o[0]) + recv;
            }
            // lane (g,r) holds the summed output for dim 16r + bitrev4(g)
            const int w = ((g & 1) << 3) | ((g & 2) << 1) | ((g & 4) >> 1) | ((g & 8) >> 3);
            if (node < N_NODES)
                out[(size_t)node * 64 + 16 * r + w] = o[0] / ((w < 8) ? sa : sb);

            node = noden; d = dN; qv0 = nq0; qv1 = nq1;
        }
    }
}

extern "C" void kernel_launch(void* const* d_in, const int* in_sizes, int n_in,
                              void* d_out, int out_size, void* d_ws, size_t ws_size,
                              hipStream_t stream) {
    const float* x = (const float*)d_in[0];
    const float* W = (const float*)d_in[1];
    // d_in[2] = batch (unused by reference)
    const int* ei = (const int*)d_in[3];
    const int* dest = ei + E_EDGES;  // ei[1]
    float* out = (float*)d_out;

    unsigned short* qkv = (unsigned short*)d_ws;                    // 19.2 MB scratch
    unsigned int* bar = (unsigned int*)((char*)d_ws + (size_t)N_NODES * FTOT * 2);

    hipMemsetAsync(bar, 0, 4, stream);   // reset barrier counter (ws is re-poisoned)
    fused<<<NBLK, 256, 0, stream>>>(x, W, dest, qkv, bar, out);
}

// Round 6
// 129.315 us; speedup vs baseline: 2.1858x; 2.1858x over previous
//
#include <hip/hip_runtime.h>
#include <math.h>

#define N_NODES 50000
#define DEG 16
#define E_EDGES (N_NODES * DEG)
#define FIN 128
#define FTOT 192   // 2*FQK + FV
#define FQK 64
#define FV 64
#define H 8

typedef __attribute__((ext_vector_type(8))) short short8;
typedef __attribute__((ext_vector_type(4))) float float4v;

__device__ inline unsigned short f2bf(float f) {
    unsigned int u = __float_as_uint(f);
    unsigned int r = u + 0x7fffu + ((u >> 16) & 1u);  // RNE
    return (unsigned short)(r >> 16);
}

#define LDC 194   // 192 + 2 bf16 pad for the epilogue transpose

// ---------- one-time W prep: fp32 [128][192] -> bf16 image Wb[n][k] = [192][128] ----------
__global__ __launch_bounds__(256) void wprep(const float* __restrict__ W,
                                             unsigned short* __restrict__ Wb) {
    const int t = blockIdx.x * 256 + threadIdx.x;   // 0..3071
    const int n = t % 192, kg = t / 192;            // kg 0..15
    unsigned short tmp[8];
#pragma unroll
    for (int j = 0; j < 8; j++)
        tmp[j] = f2bf(W[(kg * 8 + j) * FTOT + n]);  // lanes sweep n: coalesced reads
    *(uint4*)(Wb + n * FIN + kg * 8) = *(const uint4*)tmp;
}

// ---------- GEMM v2: B-fragments direct from L2, no staging barriers ----------
// Per-block critical path was the bottleneck (3-barrier lock-step chain, ~25us wall
// at 3 blocks/CU single-residency). Wb (48KB bf16) is L2-resident: read B fragments
// directly with dwordx4 (identical addresses/data to the old ds_read path), deleting
// the LDS staging loop and two of the three __syncthreads. LDS only holds the
// epilogue transpose tile (24832B -> 6 blocks/CU).
__global__ __launch_bounds__(256) void gemm_qkv(const float* __restrict__ x,
                                                const unsigned short* __restrict__ Wb,
                                                unsigned short* __restrict__ qkv) {
    __shared__ unsigned short Ct[64 * LDC];   // 24832 B
    const int tid = threadIdx.x;
    const int wave = tid >> 6, lane = tid & 63;
    const int m = lane & 15, q = lane >> 4;
    const int row = blockIdx.x * 64 + wave * 16 + m;
    const int rowc = min(row, N_NODES - 1);

    // A fragments: lane holds x[row][ s*32 + q*8 .. +7 ]
    short8 a[4];
    const float* xr = x + (size_t)rowc * FIN;
#pragma unroll
    for (int s = 0; s < 4; s++) {
        float4v f0 = *(const float4v*)(xr + s * 32 + q * 8);
        float4v f1 = *(const float4v*)(xr + s * 32 + q * 8 + 4);
        short8 av;
        av[0] = (short)f2bf(f0.x); av[1] = (short)f2bf(f0.y);
        av[2] = (short)f2bf(f0.z); av[3] = (short)f2bf(f0.w);
        av[4] = (short)f2bf(f1.x); av[5] = (short)f2bf(f1.y);
        av[6] = (short)f2bf(f1.z); av[7] = (short)f2bf(f1.w);
        a[s] = av;
    }

    float4v acc[12];
#pragma unroll
    for (int ct = 0; ct < 12; ct++) acc[ct] = (float4v){0.f, 0.f, 0.f, 0.f};

    // MFMA loop: B fragment = Wb[n = ct*16+m][k = s*32 + q*8 ..+7], straight from L2.
    // Fully unrolled so the compiler pipelines loads for ct+1 under ct's MFMAs.
#pragma unroll
    for (int ct = 0; ct < 12; ct++) {
        const unsigned short* bp = Wb + (ct * 16 + m) * FIN + q * 8;
#pragma unroll
        for (int s = 0; s < 4; s++) {
            const short8 b = *(const short8*)(bp + s * 32);
            acc[ct] = __builtin_amdgcn_mfma_f32_16x16x32_bf16(a[s], b, acc[ct], 0, 0, 0);
        }
    }

    // transpose into interleaved-layout LDS tile (q pre-scaled)
    const int lrow0 = wave * 16 + q * 4;
#pragma unroll
    for (int ct = 0; ct < 12; ct++) {
        const int col = ct * 16 + m;
        int off; float scale;
        if (col < FQK)          { off = col;                      scale = 0.35355339059327373f; }
        else if (col < 2 * FQK) { off = 64 + 2 * (col - 64);      scale = 1.f; }  // k
        else                    { off = 64 + 2 * (col - 128) + 1; scale = 1.f; }  // v
#pragma unroll
        for (int i = 0; i < 4; i++)
            Ct[(lrow0 + i) * LDC + off] = f2bf(acc[ct][i] * scale);
    }
    __syncthreads();   // the only barrier in the kernel

    // coalesced store: 64 rows x 96 dwords
    unsigned int* qg = (unsigned int*)qkv;
    const int base = blockIdx.x * 64;
#pragma unroll
    for (int i = 0; i < 24; i++) {
        int l = tid + i * 256;
        int r = l / 96, dw = l - r * 96;
        if (base + r < N_NODES)
            qg[(size_t)(base + r) * 96 + dw] = *(const unsigned int*)(&Ct[r * LDC + 2 * dw]);
    }
}

// ---------- attention v3 (best measured): one wave per node, 4 lanes per edge ----------
// lane = 4*g + r: edge g (0..15), quarter r owns heads 2r,2r+1 (dims 16r..16r+15).
// All 16 edge gathers issue immediately; q.k dot is lane-local; softmax and output
// reduce via butterflies with all-static indices.
__global__ __launch_bounds__(256) void attn(const unsigned short* __restrict__ qkv,
                                            const int* __restrict__ dest,
                                            float* __restrict__ out) {
    const int node = blockIdx.x * 4 + (threadIdx.x >> 6);
    const int lane = threadIdx.x & 63;
    const int g = lane >> 2;
    const int r = lane & 3;
    if (node >= N_NODES) return;   // wave-uniform

    const int d = dest[node * DEG + g];

    const unsigned short* qp = qkv + (size_t)node * FTOT + 16 * r;  // pre-scaled q
    const uint4 qv0 = *(const uint4*)(qp);
    const uint4 qv1 = *(const uint4*)(qp + 8);

    const unsigned short* kp = qkv + (size_t)d * FTOT + 64 + 32 * r;  // kv interleaved
    const uint4 kv0 = *(const uint4*)(kp);
    const uint4 kv1 = *(const uint4*)(kp + 8);
    const uint4 kv2 = *(const uint4*)(kp + 16);
    const uint4 kv3 = *(const uint4*)(kp + 24);

    const unsigned int qw[8]  = {qv0.x, qv0.y, qv0.z, qv0.w, qv1.x, qv1.y, qv1.z, qv1.w};
    const unsigned int kvw[16] = {kv0.x, kv0.y, kv0.z, kv0.w, kv1.x, kv1.y, kv1.z, kv1.w,
                                  kv2.x, kv2.y, kv2.z, kv2.w, kv3.x, kv3.y, kv3.z, kv3.w};
    // kvw[u] = { k[16r+u] (lo), v[16r+u] (hi) }

    float la = 0.f, lb = 0.f;   // logits for heads 2r, 2r+1 of edge g
#pragma unroll
    for (int f = 0; f < 8; f++) {
        const unsigned int qa = qw[f >> 1];
        const unsigned int qb = qw[(f + 8) >> 1];
        const float qfa = __uint_as_float((f & 1) ? (qa & 0xffff0000u) : (qa << 16));
        const float qfb = __uint_as_float((f & 1) ? (qb & 0xffff0000u) : (qb << 16));
        la = fmaf(qfa, __uint_as_float(kvw[f] << 16), la);
        lb = fmaf(qfb, __uint_as_float(kvw[f + 8] << 16), lb);
    }

    // per-head max over the 16 edges (lanes with equal r, xor over g-bits)
    float ma = la, mb = lb;
    ma = fmaxf(ma, __shfl_xor(ma, 4, 64));  mb = fmaxf(mb, __shfl_xor(mb, 4, 64));
    ma = fmaxf(ma, __shfl_xor(ma, 8, 64));  mb = fmaxf(mb, __shfl_xor(mb, 8, 64));
    ma = fmaxf(ma, __shfl_xor(ma, 16, 64)); mb = fmaxf(mb, __shfl_xor(mb, 16, 64));
    ma = fmaxf(ma, __shfl_xor(ma, 32, 64)); mb = fmaxf(mb, __shfl_xor(mb, 32, 64));
    const float pa = __expf(la - ma);
    const float pb = __expf(lb - mb);
    float sa = pa, sb = pb;
    sa += __shfl_xor(sa, 4, 64);  sb += __shfl_xor(sb, 4, 64);
    sa += __shfl_xor(sa, 8, 64);  sb += __shfl_xor(sb, 8, 64);
    sa += __shfl_xor(sa, 16, 64); sb += __shfl_xor(sb, 16, 64);
    sa += __shfl_xor(sa, 32, 64); sb += __shfl_xor(sb, 32, 64);

    // weighted v contribution of this edge, then distributed butterfly sum.
    float o[16];
#pragma unroll
    for (int w = 0; w < 8; w++) {
        o[w]     = pa * __uint_as_float(kvw[w] & 0xffff0000u);
        o[w + 8] = pb * __uint_as_float(kvw[w + 8] & 0xffff0000u);
    }
    {   // round 1: m2=4, h=8
        const bool up = (lane & 4) != 0;
#pragma unroll
        for (int j = 0; j < 8; j++) {
            const float send = up ? o[j] : o[j + 8];
            const float recv = __shfl_xor(send, 4, 64);
            o[j] = (up ? o[j + 8] : o[j]) + recv;
        }
    }
    {   // round 2: m2=8, h=4
        const bool up = (lane & 8) != 0;
#pragma unroll
        for (int j = 0; j < 4; j++) {
            const float send = up ? o[j] : o[j + 4];
            const float recv = __shfl_xor(send, 8, 64);
            o[j] = (up ? o[j + 4] : o[j]) + recv;
        }
    }
    {   // round 3: m2=16, h=2
        const bool up = (lane & 16) != 0;
#pragma unroll
        for (int j = 0; j < 2; j++) {
            const float send = up ? o[j] : o[j + 2];
            const float recv = __shfl_xor(send, 16, 64);
            o[j] = (up ? o[j + 2] : o[j]) + recv;
        }
    }
    {   // round 4: m2=32, h=1
        const bool up = (lane & 32) != 0;
        const float send = up ? o[0] : o[1];
        const float recv = __shfl_xor(send, 32, 64);
        o[0] = (up ? o[1] : o[0]) + recv;
    }
    // lane (g,r) now holds the summed output for dim 16r + bitrev4(g)
    const int w = ((g & 1) << 3) | ((g & 2) << 1) | ((g & 4) >> 1) | ((g & 8) >> 3);
    out[(size_t)node * 64 + 16 * r + w] = o[0] / ((w < 8) ? sa : sb);
}

extern "C" void kernel_launch(void* const* d_in, const int* in_sizes, int n_in,
                              void* d_out, int out_size, void* d_ws, size_t ws_size,
                              hipStream_t stream) {
    const float* x = (const float*)d_in[0];
    const float* W = (const float*)d_in[1];
    // d_in[2] = batch (unused by reference)
    const int* ei = (const int*)d_in[3];
    const int* dest = ei + E_EDGES;  // ei[1]
    float* out = (float*)d_out;

    unsigned short* qkv = (unsigned short*)d_ws;                    // 19.2 MB
    unsigned short* Wb  = qkv + (size_t)N_NODES * FTOT;             // +48 KB bf16 W image

    wprep<<<12, 256, 0, stream>>>(W, Wb);
    gemm_qkv<<<(N_NODES + 63) / 64, 256, 0, stream>>>(x, Wb, qkv);
    attn<<<(N_NODES + 3) / 4, 256, 0, stream>>>(qkv, dest, out);
}

// Round 7
// 113.861 us; speedup vs baseline: 2.4825x; 1.1357x over previous
//
#include <hip/hip_runtime.h>
#include <math.h>

#define N_NODES 50000
#define DEG 16
#define E_EDGES (N_NODES * DEG)
#define FIN 128
#define FTOT 192   // 2*FQK + FV
#define FQK 64
#define FV 64
#define H 8

typedef __attribute__((ext_vector_type(8))) short short8;
typedef __attribute__((ext_vector_type(4))) float float4v;

__device__ inline unsigned short f2bf(float f) {
    unsigned int u = __float_as_uint(f);
    unsigned int r = u + 0x7fffu + ((u >> 16) & 1u);  // RNE
    return (unsigned short)(r >> 16);
}

#define LDC 194   // 192 + 2 bf16 pad for the epilogue transpose

// ---------- one-time W prep: fp32 [128][192] -> bf16 image Wb[n][k] = [192][128] ----------
__global__ __launch_bounds__(256) void wprep(const float* __restrict__ W,
                                             unsigned short* __restrict__ Wb) {
    const int t = blockIdx.x * 256 + threadIdx.x;   // 0..3071
    const int n = t % 192, kg = t / 192;            // kg 0..15
    unsigned short tmp[8];
#pragma unroll
    for (int j = 0; j < 8; j++)
        tmp[j] = f2bf(W[(kg * 8 + j) * FTOT + n]);  // lanes sweep n: coalesced reads
    *(uint4*)(Wb + n * FIN + kg * 8) = *(const uint4*)tmp;
}

// ---------- GEMM v3: staged-LDS B in two 96-col halves -> 6 blocks/CU residency ----------
// Round-2's 49KB LDS allowed only 3 blocks/CU: capacity 768 < 782 blocks -> TWO
// sequential residency rounds for a latency-bound single-shot kernel. Halving the
// LDS (stage 96 cols at a time, 24832B total incl. Ct reuse) doubles residency so
// all 782 blocks run in ONE round. Staging math identical to round-5 phase A
// (passed); epilogue/store identical to round 2 (passed).
__global__ __launch_bounds__(256, 4) void gemm_qkv(const float* __restrict__ x,
                                                   const unsigned short* __restrict__ Wb,
                                                   unsigned short* __restrict__ qkv) {
    __shared__ unsigned short Bt[12416];   // 24832 B: B half-image (24576) / Ct (24832)
    const int tid = threadIdx.x;
    const int wave = tid >> 6, lane = tid & 63;
    const int m = lane & 15, q = lane >> 4;
    const int row = blockIdx.x * 64 + wave * 16 + m;
    const int rowc = min(row, N_NODES - 1);

    // A fragments first so x-load (HBM) latency hides under the first staging pass
    short8 a[4];
    const float* xr = x + (size_t)rowc * FIN;
#pragma unroll
    for (int s = 0; s < 4; s++) {
        float4v f0 = *(const float4v*)(xr + s * 32 + q * 8);
        float4v f1 = *(const float4v*)(xr + s * 32 + q * 8 + 4);
        short8 av;
        av[0] = (short)f2bf(f0.x); av[1] = (short)f2bf(f0.y);
        av[2] = (short)f2bf(f0.z); av[3] = (short)f2bf(f0.w);
        av[4] = (short)f2bf(f1.x); av[5] = (short)f2bf(f1.y);
        av[6] = (short)f2bf(f1.z); av[7] = (short)f2bf(f1.w);
        a[s] = av;
    }

    float4v acc[12];
#pragma unroll
    for (int ct = 0; ct < 12; ct++) acc[ct] = (float4v){0.f, 0.f, 0.f, 0.f};

    // two halves of 96 cols: stage Wb half (bf16 copy, XOR-swizzled) then 6 col-tiles
#pragma unroll
    for (int h = 0; h < 2; h++) {
#pragma unroll
        for (int i = 0; i < 6; i++) {
            const int cl = i * 256 + tid;             // local chunk 0..1535
            const int nloc = cl >> 4, kg = cl & 15;   // local col, k-group
            const uint4 v = *(const uint4*)(Wb + (h * 96 + nloc) * FIN + kg * 8);
            const int cs = cl ^ (nloc & 7);           // XOR swizzle (same as round 2)
            *(uint4*)(&Bt[cs * 8]) = v;
        }
        __syncthreads();
#pragma unroll
        for (int j = 0; j < 6; j++) {
            const int nl = j * 16 + m;                // local col in this half
            const int sw = (nl & 7) << 4;
#pragma unroll
            for (int s = 0; s < 4; s++) {
                const short8 b = *(const short8*)((const char*)Bt +
                                 (((nl << 8) + s * 64 + q * 16) ^ sw));
                acc[h * 6 + j] =
                    __builtin_amdgcn_mfma_f32_16x16x32_bf16(a[s], b, acc[h * 6 + j], 0, 0, 0);
            }
        }
        __syncthreads();   // reads done; safe to overwrite Bt (next half / Ct)
    }

    // transpose into interleaved-layout LDS tile (q pre-scaled)
    // acc[h*6+j] holds col h*96+j*16+m == (h*6+j)*16+m  (96 == 6*16)
    unsigned short* Ct = Bt;
    const int lrow0 = wave * 16 + q * 4;
#pragma unroll
    for (int ct = 0; ct < 12; ct++) {
        const int col = ct * 16 + m;
        int off; float scale;
        if (col < FQK)          { off = col;                      scale = 0.35355339059327373f; }
        else if (col < 2 * FQK) { off = 64 + 2 * (col - 64);      scale = 1.f; }  // k
        else                    { off = 64 + 2 * (col - 128) + 1; scale = 1.f; }  // v
#pragma unroll
        for (int i = 0; i < 4; i++)
            Ct[(lrow0 + i) * LDC + off] = f2bf(acc[ct][i] * scale);
    }
    __syncthreads();

    // coalesced store: 64 rows x 96 dwords
    unsigned int* qg = (unsigned int*)qkv;
    const int base = blockIdx.x * 64;
#pragma unroll
    for (int i = 0; i < 24; i++) {
        int l = tid + i * 256;
        int r = l / 96, dw = l - r * 96;
        if (base + r < N_NODES)
            qg[(size_t)(base + r) * 96 + dw] = *(const unsigned int*)(&Ct[r * LDC + 2 * dw]);
    }
}

// ---------- attention v3 (best measured): one wave per node, 4 lanes per edge ----------
// lane = 4*g + r: edge g (0..15), quarter r owns heads 2r,2r+1 (dims 16r..16r+15).
// All 16 edge gathers issue immediately; q.k dot is lane-local; softmax and output
// reduce via butterflies with all-static indices.
__global__ __launch_bounds__(256) void attn(const unsigned short* __restrict__ qkv,
                                            const int* __restrict__ dest,
                                            float* __restrict__ out) {
    const int node = blockIdx.x * 4 + (threadIdx.x >> 6);
    const int lane = threadIdx.x & 63;
    const int g = lane >> 2;
    const int r = lane & 3;
    if (node >= N_NODES) return;   // wave-uniform

    const int d = dest[node * DEG + g];

    const unsigned short* qp = qkv + (size_t)node * FTOT + 16 * r;  // pre-scaled q
    const uint4 qv0 = *(const uint4*)(qp);
    const uint4 qv1 = *(const uint4*)(qp + 8);

    const unsigned short* kp = qkv + (size_t)d * FTOT + 64 + 32 * r;  // kv interleaved
    const uint4 kv0 = *(const uint4*)(kp);
    const uint4 kv1 = *(const uint4*)(kp + 8);
    const uint4 kv2 = *(const uint4*)(kp + 16);
    const uint4 kv3 = *(const uint4*)(kp + 24);

    const unsigned int qw[8]  = {qv0.x, qv0.y, qv0.z, qv0.w, qv1.x, qv1.y, qv1.z, qv1.w};
    const unsigned int kvw[16] = {kv0.x, kv0.y, kv0.z, kv0.w, kv1.x, kv1.y, kv1.z, kv1.w,
                                  kv2.x, kv2.y, kv2.z, kv2.w, kv3.x, kv3.y, kv3.z, kv3.w};
    // kvw[u] = { k[16r+u] (lo), v[16r+u] (hi) }

    float la = 0.f, lb = 0.f;   // logits for heads 2r, 2r+1 of edge g
#pragma unroll
    for (int f = 0; f < 8; f++) {
        const unsigned int qa = qw[f >> 1];
        const unsigned int qb = qw[(f + 8) >> 1];
        const float qfa = __uint_as_float((f & 1) ? (qa & 0xffff0000u) : (qa << 16));
        const float qfb = __uint_as_float((f & 1) ? (qb & 0xffff0000u) : (qb << 16));
        la = fmaf(qfa, __uint_as_float(kvw[f] << 16), la);
        lb = fmaf(qfb, __uint_as_float(kvw[f + 8] << 16), lb);
    }

    // per-head max over the 16 edges (lanes with equal r, xor over g-bits)
    float ma = la, mb = lb;
    ma = fmaxf(ma, __shfl_xor(ma, 4, 64));  mb = fmaxf(mb, __shfl_xor(mb, 4, 64));
    ma = fmaxf(ma, __shfl_xor(ma, 8, 64));  mb = fmaxf(mb, __shfl_xor(mb, 8, 64));
    ma = fmaxf(ma, __shfl_xor(ma, 16, 64)); mb = fmaxf(mb, __shfl_xor(mb, 16, 64));
    ma = fmaxf(ma, __shfl_xor(ma, 32, 64)); mb = fmaxf(mb, __shfl_xor(mb, 32, 64));
    const float pa = __expf(la - ma);
    const float pb = __expf(lb - mb);
    float sa = pa, sb = pb;
    sa += __shfl_xor(sa, 4, 64);  sb += __shfl_xor(sb, 4, 64);
    sa += __shfl_xor(sa, 8, 64);  sb += __shfl_xor(sb, 8, 64);
    sa += __shfl_xor(sa, 16, 64); sb += __shfl_xor(sb, 16, 64);
    sa += __shfl_xor(sa, 32, 64); sb += __shfl_xor(sb, 32, 64);

    // weighted v contribution of this edge, then distributed butterfly sum.
    float o[16];
#pragma unroll
    for (int w = 0; w < 8; w++) {
        o[w]     = pa * __uint_as_float(kvw[w] & 0xffff0000u);
        o[w + 8] = pb * __uint_as_float(kvw[w + 8] & 0xffff0000u);
    }
    {   // round 1: m2=4, h=8
        const bool up = (lane & 4) != 0;
#pragma unroll
        for (int j = 0; j < 8; j++) {
            const float send = up ? o[j] : o[j + 8];
            const float recv = __shfl_xor(send, 4, 64);
            o[j] = (up ? o[j + 8] : o[j]) + recv;
        }
    }
    {   // round 2: m2=8, h=4
        const bool up = (lane & 8) != 0;
#pragma unroll
        for (int j = 0; j < 4; j++) {
            const float send = up ? o[j] : o[j + 4];
            const float recv = __shfl_xor(send, 8, 64);
            o[j] = (up ? o[j + 4] : o[j]) + recv;
        }
    }
    {   // round 3: m2=16, h=2
        const bool up = (lane & 16) != 0;
#pragma unroll
        for (int j = 0; j < 2; j++) {
            const float send = up ? o[j] : o[j + 2];
            const float recv = __shfl_xor(send, 16, 64);
            o[j] = (up ? o[j + 2] : o[j]) + recv;
        }
    }
    {   // round 4: m2=32, h=1
        const bool up = (lane & 32) != 0;
        const float send = up ? o[0] : o[1];
        const float recv = __shfl_xor(send, 32, 64);
        o[0] = (up ? o[1] : o[0]) + recv;
    }
    // lane (g,r) now holds the summed output for dim 16r + bitrev4(g)
    const int w = ((g & 1) << 3) | ((g & 2) << 1) | ((g & 4) >> 1) | ((g & 8) >> 3);
    out[(size_t)node * 64 + 16 * r + w] = o[0] / ((w < 8) ? sa : sb);
}

extern "C" void kernel_launch(void* const* d_in, const int* in_sizes, int n_in,
                              void* d_out, int out_size, void* d_ws, size_t ws_size,
                              hipStream_t stream) {
    const float* x = (const float*)d_in[0];
    const float* W = (const float*)d_in[1];
    // d_in[2] = batch (unused by reference)
    const int* ei = (const int*)d_in[3];
    const int* dest = ei + E_EDGES;  // ei[1]
    float* out = (float*)d_out;

    unsigned short* qkv = (unsigned short*)d_ws;                    // 19.2 MB
    unsigned short* Wb  = qkv + (size_t)N_NODES * FTOT;             // +48 KB bf16 W image

    wprep<<<12, 256, 0, stream>>>(W, Wb);
    gemm_qkv<<<(N_NODES + 63) / 64, 256, 0, stream>>>(x, Wb, qkv);
    attn<<<(N_NODES + 3) / 4, 256, 0, stream>>>(qkv, dest, out);
}